// Round 8
// baseline (138.168 us; speedup 1.0000x reference)
//
#include <hip/hip_runtime.h>

#define T_DIM 512
#define B_DIM 128
#define E_DIM 256
#define NEG_INF (-1e30f)
#define NB 8     // batch slots per id (covers chains <=8 in one global round-trip)

typedef float vfloat4 __attribute__((ext_vector_type(4)));  // native vec for nt-store

// Closed-form stack math (exact max-plus identity):
//   rc_t[tau] = S[t] + max_{m in [tau,t]} g[m],  S = incl. prefix sum of (d-u),
//   g[m] = d[m] - S[m].
//   W[t][tau] != 0 only at right-to-left records of g (NGL chain from t),
//   truncated once S[t] + g[m] >= 1.
// R7 insight: per-step effective latency ~2500cy (queue-inflated) on the
// SERIAL node->row global chase is the limiter. Fix: stage the block's whole
// node table (4KB) in LDS, walk chains at LDS latency, batch (wt,m) into
// registers, then issue all v-row loads INDEPENDENTLY (one round-trip/batch).

struct Node { float g; int ngl; };   // g value + next-greater-to-left index

// Kernel 1: per-b prep. Shuffle wave-scan for S; sparse-table (range-max
// binary descend) for NGL: fixed 10 LDS probes per thread, no divergent scans.
__global__ void __launch_bounds__(512) scan_prep(
    const float* __restrict__ u, const float* __restrict__ d,
    float* __restrict__ S_out, Node* __restrict__ nodes)
{
    const int b    = blockIdx.x;
    const int t    = threadIdx.x;
    const int lane = t & 63;
    const int w    = t >> 6;          // 8 waves

    __shared__ float wsum[8];
    __shared__ float wpre[8];
    __shared__ float M[10][T_DIM];    // M[k][i] = max g over [max(0,i-2^k+1), i]

    const float dv = d[t * B_DIM + b];
    float x = dv - u[t * B_DIM + b];

    // wave-level inclusive scan (6 shfl steps)
    #pragma unroll
    for (int off = 1; off < 64; off <<= 1) {
        float y = __shfl_up(x, off, 64);
        if (lane >= off) x += y;
    }
    if (lane == 63) wsum[w] = x;
    __syncthreads();
    if (t < 8) {                       // tiny exclusive scan of 8 wave totals
        float s = 0.f;
        for (int i = 0; i < t; ++i) s += wsum[i];
        wpre[t] = s;
    }
    __syncthreads();
    const float S = x + wpre[w];       // inclusive prefix sum of (d-u)
    const float g = dv - S;

    // build sparse table: 9 levels of doubling window max
    M[0][t] = g;
    __syncthreads();
    #pragma unroll
    for (int k = 1; k < 10; ++k) {
        int h = 1 << (k - 1);
        float left = (t >= h) ? M[k - 1][t - h] : NEG_INF;
        float mk = fmaxf(M[k - 1][t], left);
        __syncthreads();               // level k-1 reads done
        M[k][t] = mk;
        __syncthreads();
    }

    // binary descend: largest m < t with g[m] > g (strict); else -1.
    int m = t - 1;
    #pragma unroll
    for (int k = 9; k >= 0; --k) {
        if (m >= 0 && M[k][m] <= g) m -= (1 << k);
    }
    if (m < 0) m = -1;

    S_out[(b << 9) | t] = S;
    nodes[(b << 9) | t] = Node{g, m};
}

// Kernel 2: one block = (b, 16 consecutive t), 8 waves x 2 ids. Node table
// for b staged to LDS once; per-id chain walked at LDS latency into an
// NB-slot register batch (static-indexed); 16 independent v-row loads per
// batch, then FMA. XCD-chunked swizzle + nt stores kept from R4.
__global__ void __launch_bounds__(512) stack_read(
    const float* __restrict__ v, const float* __restrict__ S_in,
    const Node* __restrict__ nodes, float* __restrict__ out)
{
    __shared__ float2 snode[T_DIM];    // 4 KB: {g, ngl-as-float-bits}

    const int bid = blockIdx.x;                        // 0..4095
    const int swz = ((bid & 7) << 9) | (bid >> 3);     // XCD-chunked (8 XCDs)
    const int base_id = swz << 4;                      // 16 ids per block
    const int b  = base_id >> 9;                       // uniform per block
    const int wv = threadIdx.x >> 6;                   // wave 0..7
    const int lane = threadIdx.x & 63;
    const int e4 = lane << 2;

    // stage node table for this b (512 x 8B, one load per thread)
    {
        const int i = threadIdx.x;                     // 0..511
        const Node nd = nodes[(b << 9) | i];
        snode[i] = make_float2(nd.g, __int_as_float(nd.ngl));
    }
    __syncthreads();

    const int id0 = base_id | (wv << 1), id1 = id0 | 1;
    const int t0 = id0 & 511, t1 = id1 & 511;
    const float S0 = S_in[id0];
    const float S1 = S_in[id1];
    const float* __restrict__ vb = v + (size_t)b * E_DIM + e4;   // + (m<<15)

    float4 acc0 = {0.f,0.f,0.f,0.f}, acc1 = {0.f,0.f,0.f,0.f};
    float prev0 = 0.f, prev1 = 0.f;
    int m0 = t0, m1 = t1;
    bool act0 = true, act1 = true;

    while (act0 || act1) {
        float wts0[NB], wts1[NB];
        int   ms0[NB],  ms1[NB];

        // ---- walk phase: LDS-latency chain steps, two ids interleaved ----
        #pragma unroll
        for (int k = 0; k < NB; ++k) {
            if (act0) {
                const float2 nd = snode[m0];
                const float rc = S0 + nd.x;
                const float cur = fminf(rc, 1.f);
                wts0[k] = cur - prev0; prev0 = cur;
                ms0[k] = m0;
                const int ngl = __float_as_int(nd.y);
                if (rc >= 1.f || ngl < 0) act0 = false; else m0 = ngl;
            } else { wts0[k] = 0.f; ms0[k] = m0; }
            if (act1) {
                const float2 nd = snode[m1];
                const float rc = S1 + nd.x;
                const float cur = fminf(rc, 1.f);
                wts1[k] = cur - prev1; prev1 = cur;
                ms1[k] = m1;
                const int ngl = __float_as_int(nd.y);
                if (rc >= 1.f || ngl < 0) act1 = false; else m1 = ngl;
            } else { wts1[k] = 0.f; ms1[k] = m1; }
        }

        // ---- gather phase: 16 INDEPENDENT row loads, then FMA ----
        float4 va0[NB], va1[NB];
        #pragma unroll
        for (int k = 0; k < NB; ++k) {
            va0[k] = *(const float4*)(vb + ((size_t)ms0[k] << 15));
            va1[k] = *(const float4*)(vb + ((size_t)ms1[k] << 15));
        }
        #pragma unroll
        for (int k = 0; k < NB; ++k) {
            acc0.x += wts0[k] * va0[k].x; acc0.y += wts0[k] * va0[k].y;
            acc0.z += wts0[k] * va0[k].z; acc0.w += wts0[k] * va0[k].w;
            acc1.x += wts1[k] * va1[k].x; acc1.y += wts1[k] * va1[k].y;
            acc1.z += wts1[k] * va1[k].z; acc1.w += wts1[k] * va1[k].w;
        }
    }

    // nt stores: write-once stream, keep out of L2/L3 so v rows stay resident
    const vfloat4 o0 = {acc0.x, acc0.y, acc0.z, acc0.w};
    const vfloat4 o1 = {acc1.x, acc1.y, acc1.z, acc1.w};
    __builtin_nontemporal_store(o0,
        (vfloat4*)(out + ((size_t)t0 * B_DIM + b) * E_DIM + e4));
    __builtin_nontemporal_store(o1,
        (vfloat4*)(out + ((size_t)t1 * B_DIM + b) * E_DIM + e4));
}

extern "C" void kernel_launch(void* const* d_in, const int* in_sizes, int n_in,
                              void* d_out, int out_size, void* d_ws, size_t ws_size,
                              hipStream_t stream) {
    const float* v = (const float*)d_in[0];
    const float* u = (const float*)d_in[1];
    const float* d = (const float*)d_in[2];
    float* out = (float*)d_out;

    float* S    = (float*)d_ws;                                     // 256 KB
    Node*  node = (Node*)((char*)d_ws + (size_t)B_DIM * T_DIM * 4); // 512 KB

    scan_prep<<<dim3(B_DIM), 512, 0, stream>>>(u, d, S, node);
    stack_read<<<dim3((T_DIM * B_DIM) / 16), 512, 0, stream>>>(v, S, node, out);
}

// Round 9
// 126.949 us; speedup vs baseline: 1.0884x; 1.0884x over previous
//
#include <hip/hip_runtime.h>

#define T_DIM 512
#define B_DIM 128
#define E_DIM 256
#define NEG_INF (-1e30f)
#define W 8          // ids (consecutive t) per wave
#define DONE 1e30f

typedef float vfloat4 __attribute__((ext_vector_type(4)));  // native vec for nt-store

// Closed-form stack math (exact max-plus identity):
//   rc_t[tau] = S[t] + max_{m in [tau,t]} g[m],  S = incl. prefix sum of (d-u),
//   g[m] = d[m] - S[m].
//   W[t][tau] != 0 only at right-to-left records of g (NGL chain from t),
//   truncated once S[t] + g[m] >= 1.
// R8 insight: time tracks CACHE-HIERARCHY row bytes (~295MB @ ~7TB/s), not HBM
// bytes, not latency. Fix: descending-m sweep per 8-id window. Window rows load
// once; below-window rows come from the SHARED union chain (= chain of the
// min-running-max id, enumerated via ngl links + threshold skip, all in LDS).
// Per-id op sequence identical to the chase -> bit-exact.

struct Node { float g; int ngl; };   // g value + next-greater-to-left index

// Kernel 1: per-b prep. Shuffle wave-scan for S; sparse-table (range-max
// binary descend) for NGL: fixed 10 LDS probes per thread, no divergent scans.
__global__ void __launch_bounds__(512) scan_prep(
    const float* __restrict__ u, const float* __restrict__ d,
    float* __restrict__ S_out, Node* __restrict__ nodes)
{
    const int b    = blockIdx.x;
    const int t    = threadIdx.x;
    const int lane = t & 63;
    const int w    = t >> 6;          // 8 waves

    __shared__ float wsum[8];
    __shared__ float wpre[8];
    __shared__ float M[10][T_DIM];    // M[k][i] = max g over [max(0,i-2^k+1), i]

    const float dv = d[t * B_DIM + b];
    float x = dv - u[t * B_DIM + b];

    // wave-level inclusive scan (6 shfl steps)
    #pragma unroll
    for (int off = 1; off < 64; off <<= 1) {
        float y = __shfl_up(x, off, 64);
        if (lane >= off) x += y;
    }
    if (lane == 63) wsum[w] = x;
    __syncthreads();
    if (t < 8) {                       // tiny exclusive scan of 8 wave totals
        float s = 0.f;
        for (int i = 0; i < t; ++i) s += wsum[i];
        wpre[t] = s;
    }
    __syncthreads();
    const float S = x + wpre[w];       // inclusive prefix sum of (d-u)
    const float g = dv - S;

    // build sparse table: 9 levels of doubling window max
    M[0][t] = g;
    __syncthreads();
    #pragma unroll
    for (int k = 1; k < 10; ++k) {
        int h = 1 << (k - 1);
        float left = (t >= h) ? M[k - 1][t - h] : NEG_INF;
        float mk = fmaxf(M[k - 1][t], left);
        __syncthreads();               // level k-1 reads done
        M[k][t] = mk;
        __syncthreads();
    }

    // binary descend: largest m < t with g[m] > g (strict); else -1.
    int m = t - 1;
    #pragma unroll
    for (int k = 9; k >= 0; --k) {
        if (m >= 0 && M[k][m] <= g) m -= (1 << k);
    }
    if (m < 0) m = -1;

    S_out[(b << 9) | t] = S;
    nodes[(b << 9) | t] = Node{g, m};
}

// Kernel 2: one wave = 8 consecutive t of one b; block = 4 waves = 32 t;
// grid 2048 (XCD-chunked swizzle). Node table in LDS (4KB). Descending-m
// sweep: g > M[j] filter IS the record condition -> per-id math identical
// to the chase. Window rows 1x each; below-window rows shared via union
// chain (ngl links + threshold skip). nt-stores for the write-once out.
__global__ void __launch_bounds__(256) stack_read(
    const float* __restrict__ v, const float* __restrict__ S_in,
    const Node* __restrict__ nodes, float* __restrict__ out)
{
    __shared__ float2 snode[T_DIM];    // 4 KB: {g, ngl-as-float-bits}

    const int bid = blockIdx.x;                      // 0..2047
    const int swz = ((bid & 7) << 8) | (bid >> 3);   // XCD-chunked (8 XCDs)
    const int base_id = swz << 5;                    // 32 ids per block
    const int b    = base_id >> 9;                   // uniform per block
    const int wv   = threadIdx.x >> 6;               // wave 0..3
    const int lane = threadIdx.x & 63;
    const int e4   = lane << 2;

    {   // stage node table for this b (512 x 8B, two loads per thread)
        const int i = threadIdx.x;                   // 0..255
        const Node n0 = nodes[(b << 9) | i];
        const Node n1 = nodes[(b << 9) | (i + 256)];
        snode[i]       = make_float2(n0.g, __int_as_float(n0.ngl));
        snode[i + 256] = make_float2(n1.g, __int_as_float(n1.ngl));
    }
    __syncthreads();

    const int tw = (base_id & 511) | (wv << 3);      // window start t
    const float* __restrict__ vb = v + (size_t)b * E_DIM + e4;   // + (m<<15)

    float4 acc[W];
    float  M[W], prev[W], S[W];
    #pragma unroll
    for (int j = 0; j < W; ++j) {
        acc[j] = make_float4(0.f, 0.f, 0.f, 0.f);
        M[j] = NEG_INF; prev[j] = 0.f;
        S[j] = S_in[base_id + (wv << 3) + j];
    }

    // Phase A: window rows m = tw+7 .. tw, each loaded exactly once.
    #pragma unroll
    for (int k = W - 1; k >= 0; --k) {
        const int m = tw + k;
        const float2 nd = snode[m];
        const float g = nd.x;
        const float4 vv = *(const float4*)(vb + ((size_t)m << 15));
        #pragma unroll
        for (int j = 0; j < W; ++j) {
            if (j >= k) {                            // m <= t_j
                if (g > M[j]) {                      // record condition
                    const float rc  = S[j] + g;
                    const float cur = fminf(rc, 1.f);
                    const float wt  = cur - prev[j];
                    acc[j].x += wt * vv.x; acc[j].y += wt * vv.y;
                    acc[j].z += wt * vv.z; acc[j].w += wt * vv.w;
                    prev[j] = cur;
                    M[j] = (rc >= 1.f) ? DONE : g;
                }
            }
        }
    }

    // Phase B: shared below-window union chain.
    float thr = M[0];
    #pragma unroll
    for (int j = 1; j < W; ++j) thr = fminf(thr, M[j]);

    if (thr < 1e29f) {
        int p = __float_as_int(snode[tw].y);         // ngl(tw)
        while (p >= 0) {                             // skip to first > thr
            const float2 nd = snode[p];
            if (nd.x > thr) break;
            p = __float_as_int(nd.y);
        }
        while (p >= 0) {
            const float2 nd = snode[p];
            const float g = nd.x;
            const float4 vv = *(const float4*)(vb + ((size_t)p << 15));
            #pragma unroll
            for (int j = 0; j < W; ++j) {
                if (g > M[j]) {
                    const float rc  = S[j] + g;
                    const float cur = fminf(rc, 1.f);
                    const float wt  = cur - prev[j];
                    acc[j].x += wt * vv.x; acc[j].y += wt * vv.y;
                    acc[j].z += wt * vv.z; acc[j].w += wt * vv.w;
                    prev[j] = cur;
                    M[j] = (rc >= 1.f) ? DONE : g;
                }
            }
            thr = M[0];
            #pragma unroll
            for (int j = 1; j < W; ++j) thr = fminf(thr, M[j]);
            if (thr > 1e29f) break;                  // all ids done
            p = __float_as_int(nd.y);
            while (p >= 0) {                         // threshold skip
                const float2 nd2 = snode[p];
                if (nd2.x > thr) break;
                p = __float_as_int(nd2.y);
            }
        }
    }

    #pragma unroll
    for (int j = 0; j < W; ++j) {
        const int t = tw + j;
        const vfloat4 o = {acc[j].x, acc[j].y, acc[j].z, acc[j].w};
        __builtin_nontemporal_store(o,
            (vfloat4*)(out + ((size_t)t * B_DIM + b) * E_DIM + e4));
    }
}

extern "C" void kernel_launch(void* const* d_in, const int* in_sizes, int n_in,
                              void* d_out, int out_size, void* d_ws, size_t ws_size,
                              hipStream_t stream) {
    const float* v = (const float*)d_in[0];
    const float* u = (const float*)d_in[1];
    const float* d = (const float*)d_in[2];
    float* out = (float*)d_out;

    float* S    = (float*)d_ws;                                     // 256 KB
    Node*  node = (Node*)((char*)d_ws + (size_t)B_DIM * T_DIM * 4); // 512 KB

    scan_prep<<<dim3(B_DIM), 512, 0, stream>>>(u, d, S, node);
    stack_read<<<dim3((T_DIM * B_DIM) / 32), 256, 0, stream>>>(v, S, node, out);
}